// Round 4
// baseline (309.850 us; speedup 1.0000x reference)
//
#include <hip/hip_runtime.h>
#include <cstdint>

static constexpr int L   = 1024;
static constexpr int B   = 16;
static constexpr int D   = 512;
static constexpr int RB  = L * B;    // 16384
static constexpr int LDR = B * D;    // 8192

typedef uint16_t u16;
typedef __attribute__((ext_vector_type(8))) short short8;
typedef __attribute__((ext_vector_type(4))) float f32x4;
struct alignas(8) U16x4 { u16 x, y, z, w; };

typedef __attribute__((address_space(1))) const unsigned int gu32;
typedef __attribute__((address_space(3))) unsigned int lu32;

__device__ __forceinline__ u16 f2bf(float f) {
    union { float f; unsigned u; } v; v.f = f;
    unsigned r = v.u + 0x7fffu + ((v.u >> 16) & 1u);
    return (u16)(r >> 16);
}

__device__ __forceinline__ short8 cvt8(float4 a0, float4 a1) {
    short8 r;
    r[0]=(short)f2bf(a0.x); r[1]=(short)f2bf(a0.y); r[2]=(short)f2bf(a0.z); r[3]=(short)f2bf(a0.w);
    r[4]=(short)f2bf(a1.x); r[5]=(short)f2bf(a1.y); r[6]=(short)f2bf(a1.z); r[7]=(short)f2bf(a1.w);
    return r;
}

__device__ __forceinline__ void async16(const u16* g, u16* l) {
    __builtin_amdgcn_global_load_lds((gu32*)g, (lu32*)l, 16, 0, 0);
}

// ---------------------------------------------------------------------------
// GEMM: 128x128 tile, BK=32, bf16 MFMA 16x16x32, fragment-ready LDS layout.
// LDS chunk index c = i16*64 + quad*16 + l16  ->  u16 offset c*8 (16B chunks).
// MODE 1: dvals[r][e]   A=X|T fp32 (reg-convert), B=W1b|W2b, K=1024
// MODE 2: PT[b][i][m]   A=W3b,  B=EncB[b][m][e],  K=512
// MODE 3: HT[b][i][e1]  A=PTb,  B=EncT[b][e][m],  K=1024
// MODE 4: out[l,b,i]    A=dvals_bf, B=HTb,        K=512
// ---------------------------------------------------------------------------
template<int MODE>
__global__ __launch_bounds__(256) void gemm_mfma(
    const float* __restrict__ Xp, const float* __restrict__ Tp,
    const u16* __restrict__ W1b, const u16* __restrict__ W2b, const u16* __restrict__ W3b,
    const u16* __restrict__ EncB, const u16* __restrict__ EncT,
    const u16* __restrict__ dvals_c, const u16* __restrict__ PT_c, const u16* __restrict__ HT_c,
    const float* __restrict__ b1, const float* __restrict__ b2, const float* __restrict__ b3,
    const float* __restrict__ Sinv,
    u16* __restrict__ Cb, float* __restrict__ Cf)
{
    constexpr int K = (MODE == 1 || MODE == 3) ? 1024 : 512;
    __shared__ __align__(16) u16 As[128 * 32];
    __shared__ __align__(16) u16 Bs[128 * 32];
    const int z    = blockIdx.z;
    const int row0 = blockIdx.y * 128;
    const int col0 = blockIdx.x * 128;
    const int tid  = threadIdx.x;
    const int lane = tid & 63, w = tid >> 6;
    const int wm = w >> 1, wn = w & 1;
    const int quad = lane >> 4, l16 = lane & 15;

    f32x4 acc[4][4] = {};

    for (int kb = 0; kb < K; kb += 32) {
        // ---- B operand: async global->LDS (bf16 source, fragment layout) ----
        #pragma unroll
        for (int c = 0; c < 2; ++c) {
            const int j16 = w * 2 + c;
            const int col = col0 + j16 * 16 + l16;
            const int kk  = kb + quad * 8;
            const u16* src;
            if constexpr (MODE == 1)      src = (kk < 512) ? (W1b + col*512 + kk) : (W2b + col*512 + kk - 512);
            else if constexpr (MODE == 2) src = EncB + z*524288 + col*512 + kk;
            else if constexpr (MODE == 3) src = EncT + z*524288 + col*1024 + kk;
            else                          src = HT_c + z*262144 + col*512 + kk;
            async16(src, &Bs[j16 * 512]);
        }
        // ---- A operand ----
        if constexpr (MODE == 1) {
            // fp32 source, convert in regs, ds_write in fragment layout
            #pragma unroll
            for (int cc = 0; cc < 2; ++cc) {
                const int c   = tid + cc * 256;
                const int i16 = c >> 6, qd = (c >> 4) & 3, r16 = c & 15;
                const int row = row0 + i16 * 16 + r16;
                const int kk  = kb + qd * 8;
                const float* src = (kk < 512) ? (Xp + row*512 + kk) : (Tp + row*512 + kk - 512);
                float4 a0 = *(const float4*)src;
                float4 a1 = *((const float4*)src + 1);
                *(short8*)&As[c * 8] = cvt8(a0, a1);
            }
        } else {
            #pragma unroll
            for (int c = 0; c < 2; ++c) {
                const int i16 = w * 2 + c;
                const int row = row0 + i16 * 16 + l16;
                const int kk  = kb + quad * 8;
                const u16* src;
                if constexpr (MODE == 2)      src = W3b + row*512 + kk;
                else if constexpr (MODE == 3) src = PT_c + z*524288 + row*1024 + kk;
                else                          src = dvals_c + (row*16 + z)*512 + kk;
                async16(src, &As[i16 * 512]);
            }
        }
        __syncthreads();
        short8 af[4], bfr[4];
        #pragma unroll
        for (int i = 0; i < 4; ++i)
            af[i] = *(const short8*)&As[(wm*4 + i)*512 + lane*8];
        #pragma unroll
        for (int j = 0; j < 4; ++j)
            bfr[j] = *(const short8*)&Bs[(wn*4 + j)*512 + lane*8];
        #pragma unroll
        for (int i = 0; i < 4; ++i)
            #pragma unroll
            for (int j = 0; j < 4; ++j)
                acc[i][j] = __builtin_amdgcn_mfma_f32_16x16x32_bf16(af[i], bfr[j], acc[i][j], 0, 0, 0);
        __syncthreads();
    }

    #pragma unroll
    for (int i = 0; i < 4; ++i) {
        const int grow = row0 + wm*64 + i*16 + quad*4;
        #pragma unroll
        for (int j = 0; j < 4; ++j) {
            const int gcol = col0 + wn*64 + j*16 + l16;
            #pragma unroll
            for (int r = 0; r < 4; ++r) {
                float v = acc[i][j][r];
                const int R = grow + r;
                if constexpr (MODE == 1) {
                    v += b1[gcol] + b2[gcol];
                    Cb[R*512 + gcol] = f2bf(v);
                } else if constexpr (MODE == 2) {
                    Cb[z*524288 + R*1024 + gcol] = f2bf(v);
                } else if constexpr (MODE == 3) {
                    Cb[z*262144 + R*512 + gcol] = f2bf(v);
                } else {
                    const float s = Sinv[R*16 + z];
                    Cf[(R*16 + z)*512 + gcol] = v * s + b3[gcol];
                }
            }
        }
    }
}

// ---------------------------------------------------------------------------
// Enc pass: per 64x64 (m,e) tile of batch b:
//   EncB[b][m][e] (straight bf16), EncT[b][e][m] (transposed bf16),
//   part[mtile][b*512+e] = fp64 column partial sums (feeds encsum).
// ---------------------------------------------------------------------------
__global__ __launch_bounds__(256) void enct_kernel(
    const float* __restrict__ E, u16* __restrict__ EncT,
    u16* __restrict__ EncB, double* __restrict__ part)
{
    __shared__ float tile[64][65];
    const int bb = blockIdx.z;
    const int m0 = blockIdx.y * 64;
    const int e0 = blockIdx.x * 64;
    const int t = threadIdx.x;
    const int tr = t >> 4;
    const int tc4 = (t & 15) * 4;
    #pragma unroll
    for (int it = 0; it < 4; ++it) {
        const int ml = tr + it*16;
        float4 v = *(const float4*)&E[(m0+ml)*LDR + bb*512 + e0 + tc4];
        *(float4*)&tile[ml][tc4] = v;
        U16x4 o; o.x=f2bf(v.x); o.y=f2bf(v.y); o.z=f2bf(v.z); o.w=f2bf(v.w);
        *(U16x4*)&EncB[bb*524288 + (m0+ml)*512 + e0 + tc4] = o;
    }
    __syncthreads();
    #pragma unroll
    for (int it = 0; it < 4; ++it) {
        const int el = tr + it*16;
        U16x4 o;
        o.x = f2bf(tile[tc4+0][el]);
        o.y = f2bf(tile[tc4+1][el]);
        o.z = f2bf(tile[tc4+2][el]);
        o.w = f2bf(tile[tc4+3][el]);
        *(U16x4*)&EncT[bb*524288 + (e0+el)*1024 + m0 + tc4] = o;
    }
    if (t < 64) {
        double a = 0.0;
        #pragma unroll
        for (int m = 0; m < 64; ++m) a += (double)tile[m][t];
        part[(m0 >> 6) * 8192 + bb*512 + e0 + t] = a;
    }
}

// weights -> bf16
__global__ __launch_bounds__(256) void castw_kernel(
    const float* __restrict__ W1, const float* __restrict__ W2, const float* __restrict__ W3,
    u16* __restrict__ W1b, u16* __restrict__ W2b, u16* __restrict__ W3b)
{
    const float* src = blockIdx.y == 0 ? W1 : (blockIdx.y == 1 ? W2 : W3);
    u16*         dst = blockIdx.y == 0 ? W1b : (blockIdx.y == 1 ? W2b : W3b);
    const int n = (blockIdx.x * 256 + threadIdx.x) * 8;
    float4 a0 = *(const float4*)&src[n];
    float4 a1 = *(const float4*)&src[n + 4];
    *(short8*)&dst[n] = cvt8(a0, a1);
}

// es[b][e] = sum of 16 partials; u[which][b][i] = sum_e W[e*512+i]*es; cd[b]
__global__ __launch_bounds__(256) void ucd_kernel(
    const float* __restrict__ W1, const float* __restrict__ W2,
    const float* __restrict__ b1, const float* __restrict__ b2,
    const double* __restrict__ part, double* __restrict__ u, double* __restrict__ cd)
{
    __shared__ double es[512];
    __shared__ double red[256];
    const int which = blockIdx.y;
    const int t = blockIdx.x * 256 + threadIdx.x;   // (b,i) flat
    const int b = t >> 9;
    const int i = t & 511;
    for (int e = threadIdx.x; e < 512; e += 256) {
        double a = 0.0;
        #pragma unroll
        for (int mt = 0; mt < 16; ++mt) a += part[mt*8192 + b*512 + e];
        es[e] = a;
    }
    __syncthreads();
    const float* W = which ? W2 : W1;
    double a = 0.0;
    for (int e = 0; e < 512; ++e) a += (double)W[e*512 + i] * es[e];
    u[which*8192 + t] = a;
    if (which == 0 && (blockIdx.x & 1) == 0) {
        double p = 0.0;
        for (int e = threadIdx.x; e < 512; e += 256) p += (double)(b1[e] + b2[e]) * es[e];
        red[threadIdx.x] = p;
        __syncthreads();
        for (int s = 128; s > 0; s >>= 1) {
            if (threadIdx.x < s) red[threadIdx.x] += red[threadIdx.x + s];
            __syncthreads();
        }
        if (threadIdx.x == 0) cd[b] = red[0];
    }
}

// Sinv[r] = 1 / ( X[r,:]·u1[b] + T[r,:]·u2[b] + c[b] ),  b = r%16, fp64
__global__ __launch_bounds__(256) void s_kernel(
    const float* __restrict__ X, const float* __restrict__ T,
    const double* __restrict__ u, const double* __restrict__ cd,
    float* __restrict__ Sinv)
{
    const int wave = threadIdx.x >> 6, lane = threadIdx.x & 63;
    const int r = blockIdx.x * 4 + wave;
    const int b = r & 15;
    const double* u1 = u + b*512;
    const double* u2 = u + 8192 + b*512;
    double a = 0.0;
    for (int e = lane*4; e < 512; e += 256) {
        float4 x  = *(const float4*)&X[r*512 + e];
        float4 t4 = *(const float4*)&T[r*512 + e];
        a += (double)x.x*u1[e] + (double)x.y*u1[e+1] + (double)x.z*u1[e+2] + (double)x.w*u1[e+3];
        a += (double)t4.x*u2[e] + (double)t4.y*u2[e+1] + (double)t4.z*u2[e+2] + (double)t4.w*u2[e+3];
    }
    #pragma unroll
    for (int off = 32; off > 0; off >>= 1) a += __shfl_down(a, off, 64);
    if (lane == 0) Sinv[r] = (float)(1.0 / (a + cd[b]));
}

extern "C" void kernel_launch(void* const* d_in, const int* in_sizes, int n_in,
                              void* d_out, int out_size, void* d_ws, size_t ws_size,
                              hipStream_t stream)
{
    const float* X   = (const float*)d_in[0];
    const float* Enc = (const float*)d_in[1];
    const float* T   = (const float*)d_in[2];
    const float* W1  = (const float*)d_in[3];
    const float* b1  = (const float*)d_in[4];
    const float* W2  = (const float*)d_in[5];
    const float* b2  = (const float*)d_in[6];
    const float* W3  = (const float*)d_in[7];
    const float* b3  = (const float*)d_in[8];
    float* out = (float*)d_out;

    char* w = (char*)d_ws;
    u16*    W1b      = (u16*)(w);                  //   512 KB
    u16*    W2b      = (u16*)(w + 524288);         //   512 KB
    u16*    W3b      = (u16*)(w + 1048576);        //   512 KB
    u16*    EncB     = (u16*)(w + 1572864);        //    16 MB
    u16*    EncT     = (u16*)(w + 18350080);       //    16 MB
    u16*    dvals_bf = (u16*)(w + 35127296);       //    16 MB
    u16*    PT_bf    = (u16*)(w + 51904512);       //    16 MB
    u16*    HT_bf    = (u16*)(w + 68681728);       //     8 MB
    double* part     = (double*)(w + 77070336);    //     1 MB
    double* u        = (double*)(w + 78118912);    //   128 KB
    double* cd       = (double*)(w + 78249984);    //   128 B
    float*  Sinv     = (float*)(w + 78250112);     //    64 KB

    dim3 blk(256);
    castw_kernel<<<dim3(128, 3),    blk, 0, stream>>>(W1, W2, W3, W1b, W2b, W3b);
    enct_kernel <<<dim3(8, 16, 16), blk, 0, stream>>>(Enc, EncT, EncB, part);
    ucd_kernel  <<<dim3(32, 2),     blk, 0, stream>>>(W1, W2, b1, b2, part, u, cd);
    s_kernel    <<<dim3(4096),      blk, 0, stream>>>(X, T, u, cd, Sinv);

    gemm_mfma<1><<<dim3(4, 128, 1), blk, 0, stream>>>(X, T, W1b, W2b, W3b, EncB, EncT,
        dvals_bf, PT_bf, HT_bf, b1, b2, b3, Sinv, dvals_bf, out);
    gemm_mfma<2><<<dim3(8, 4, 16),  blk, 0, stream>>>(X, T, W1b, W2b, W3b, EncB, EncT,
        dvals_bf, PT_bf, HT_bf, b1, b2, b3, Sinv, PT_bf, out);
    gemm_mfma<3><<<dim3(4, 4, 16),  blk, 0, stream>>>(X, T, W1b, W2b, W3b, EncB, EncT,
        dvals_bf, PT_bf, HT_bf, b1, b2, b3, Sinv, HT_bf, out);
    gemm_mfma<4><<<dim3(4, 8, 16),  blk, 0, stream>>>(X, T, W1b, W2b, W3b, EncB, EncT,
        dvals_bf, PT_bf, HT_bf, b1, b2, b3, Sinv, dvals_bf, out);
}

// Round 5
// 307.123 us; speedup vs baseline: 1.0089x; 1.0089x over previous
//
#include <hip/hip_runtime.h>
#include <cstdint>

static constexpr int L   = 1024;
static constexpr int B   = 16;
static constexpr int D   = 512;
static constexpr int RB  = L * B;    // 16384
static constexpr int LDR = B * D;    // 8192

typedef uint16_t u16;
typedef __attribute__((ext_vector_type(8))) short short8;
typedef __attribute__((ext_vector_type(4))) float f32x4;
struct alignas(8) U16x4 { u16 x, y, z, w; };

typedef __attribute__((address_space(1))) const unsigned int gu32;
typedef __attribute__((address_space(3))) unsigned int lu32;

__device__ __forceinline__ u16 f2bf(float f) {
    union { float f; unsigned u; } v; v.f = f;
    unsigned r = v.u + 0x7fffu + ((v.u >> 16) & 1u);
    return (u16)(r >> 16);
}

__device__ __forceinline__ short8 cvt8(float4 a0, float4 a1) {
    short8 r;
    r[0]=(short)f2bf(a0.x); r[1]=(short)f2bf(a0.y); r[2]=(short)f2bf(a0.z); r[3]=(short)f2bf(a0.w);
    r[4]=(short)f2bf(a1.x); r[5]=(short)f2bf(a1.y); r[6]=(short)f2bf(a1.z); r[7]=(short)f2bf(a1.w);
    return r;
}

__device__ __forceinline__ void async16(const u16* g, u16* l) {
    __builtin_amdgcn_global_load_lds((gu32*)g, (lu32*)l, 16, 0, 0);
}

// ---------------------------------------------------------------------------
// GEMM: 128x128 tile, BK=64 (two 32-k halves), bf16 MFMA 16x16x32.
// All operands bf16, staged via global_load_lds in fragment-ready layout:
//   LDS chunk (h, i16, lane) at u16 offset (h*8 + i16)*512 + lane*8.
// MODE 1: dvals[r][e]   A=XTb (lda 1024), B=W12b (ldb 1024),        K=1024
// MODE 2: PT[b][i][m]   A=W3b (512),      B=EncB[z] (512),          K=512
// MODE 3: HT[b][i][e1]  A=PT[z] (1024),   B=EncT[z] (1024),         K=1024
// MODE 4: out[l,b,i]    A=dvals (8192, +z*512), B=HT[z] (512),      K=512
// ---------------------------------------------------------------------------
template<int MODE>
__global__ __launch_bounds__(256) void gemm_mfma(
    const u16* __restrict__ A, const u16* __restrict__ Bm,
    const float* __restrict__ bias1, const float* __restrict__ bias2,
    const float* __restrict__ bias3, const float* __restrict__ Sinv,
    u16* __restrict__ Cb, float* __restrict__ Cf)
{
    constexpr int K   = (MODE == 1 || MODE == 3) ? 1024 : 512;
    constexpr int LDA = (MODE == 2) ? 512 : (MODE == 4 ? 8192 : 1024);
    constexpr int LDB = (MODE == 1 || MODE == 3) ? 1024 : 512;
    constexpr int AZ  = (MODE == 3) ? 524288 : (MODE == 4 ? 512 : 0);
    constexpr int BZ  = (MODE == 2 || MODE == 3) ? 524288 : (MODE == 4 ? 262144 : 0);

    __shared__ __align__(16) u16 As[8192];   // 16 KB
    __shared__ __align__(16) u16 Bs[8192];   // 16 KB
    const int z    = blockIdx.z;
    const int row0 = blockIdx.y * 128;
    const int col0 = blockIdx.x * 128;
    const int tid  = threadIdx.x;
    const int lane = tid & 63, w = tid >> 6;
    const int wm = w >> 1, wn = w & 1;
    const int quad = lane >> 4, l16 = lane & 15;

    const u16* Ab = A  + (long)AZ * z;
    const u16* Bb = Bm + (long)BZ * z;

    f32x4 acc[4][4] = {};

    for (int kb = 0; kb < K; kb += 64) {
        #pragma unroll
        for (int h = 0; h < 2; ++h) {
            #pragma unroll
            for (int c = 0; c < 2; ++c) {
                const int i16 = w * 2 + c;
                const int kk  = kb + h * 32 + quad * 8;
                async16(Ab + (row0 + i16*16 + l16) * LDA + kk, &As[(h*8 + i16) * 512]);
                async16(Bb + (col0 + i16*16 + l16) * LDB + kk, &Bs[(h*8 + i16) * 512]);
            }
        }
        __syncthreads();
        #pragma unroll
        for (int h = 0; h < 2; ++h) {
            short8 af[4], bfr[4];
            #pragma unroll
            for (int i = 0; i < 4; ++i)
                af[i] = *(const short8*)&As[(h*8 + wm*4 + i)*512 + lane*8];
            #pragma unroll
            for (int j = 0; j < 4; ++j)
                bfr[j] = *(const short8*)&Bs[(h*8 + wn*4 + j)*512 + lane*8];
            #pragma unroll
            for (int i = 0; i < 4; ++i)
                #pragma unroll
                for (int j = 0; j < 4; ++j)
                    acc[i][j] = __builtin_amdgcn_mfma_f32_16x16x32_bf16(af[i], bfr[j], acc[i][j], 0, 0, 0);
        }
        __syncthreads();
    }

    #pragma unroll
    for (int i = 0; i < 4; ++i) {
        const int grow = row0 + wm*64 + i*16 + quad*4;
        #pragma unroll
        for (int j = 0; j < 4; ++j) {
            const int gcol = col0 + wn*64 + j*16 + l16;
            #pragma unroll
            for (int r = 0; r < 4; ++r) {
                float v = acc[i][j][r];
                const int R = grow + r;
                if constexpr (MODE == 1) {
                    v += bias1[gcol] + bias2[gcol];
                    Cb[R*512 + gcol] = f2bf(v);
                } else if constexpr (MODE == 2) {
                    Cb[z*524288 + R*1024 + gcol] = f2bf(v);
                } else if constexpr (MODE == 3) {
                    Cb[z*262144 + R*512 + gcol] = f2bf(v);
                } else {
                    const float s = Sinv[R*16 + z];
                    Cf[(R*16 + z)*512 + gcol] = v * s + bias3[gcol];
                }
            }
        }
    }
}

// ---------------------------------------------------------------------------
// Enc pass: per 64x64 (m,e) tile of batch b: EncB bf16, EncT bf16 (transposed),
// and fp64 column partial sums into part[mtile][b*512+e].
// ---------------------------------------------------------------------------
__global__ __launch_bounds__(256) void enct_kernel(
    const float* __restrict__ E, u16* __restrict__ EncT,
    u16* __restrict__ EncB, double* __restrict__ part)
{
    __shared__ float tile[64][65];
    const int bb = blockIdx.z;
    const int m0 = blockIdx.y * 64;
    const int e0 = blockIdx.x * 64;
    const int t = threadIdx.x;
    const int tr = t >> 4;
    const int tc4 = (t & 15) * 4;
    #pragma unroll
    for (int it = 0; it < 4; ++it) {
        const int ml = tr + it*16;
        float4 v = *(const float4*)&E[(m0+ml)*LDR + bb*512 + e0 + tc4];
        *(float4*)&tile[ml][tc4] = v;
        U16x4 o; o.x=f2bf(v.x); o.y=f2bf(v.y); o.z=f2bf(v.z); o.w=f2bf(v.w);
        *(U16x4*)&EncB[bb*524288 + (m0+ml)*512 + e0 + tc4] = o;
    }
    __syncthreads();
    #pragma unroll
    for (int it = 0; it < 4; ++it) {
        const int el = tr + it*16;
        U16x4 o;
        o.x = f2bf(tile[tc4+0][el]);
        o.y = f2bf(tile[tc4+1][el]);
        o.z = f2bf(tile[tc4+2][el]);
        o.w = f2bf(tile[tc4+3][el]);
        *(U16x4*)&EncT[bb*524288 + (e0+el)*1024 + m0 + tc4] = o;
    }
    if (t < 64) {
        double a = 0.0;
        #pragma unroll
        for (int m = 0; m < 64; ++m) a += (double)tile[m][t];
        part[(m0 >> 6) * 8192 + bb*512 + e0 + t] = a;
    }
}

// weights -> bf16. W1,W2 interleave into W12b[col][0..511 | 512..1023]; W3 -> W3b.
__global__ __launch_bounds__(256) void castw_kernel(
    const float* __restrict__ W1, const float* __restrict__ W2, const float* __restrict__ W3,
    u16* __restrict__ W12b, u16* __restrict__ W3b)
{
    const int n = (blockIdx.x * 256 + threadIdx.x) * 8;   // 0..262143 step 8
    const int which = blockIdx.y;
    const int col = n >> 9, k = n & 511;
    const float* src = which == 0 ? W1 : (which == 1 ? W2 : W3);
    float4 a0 = *(const float4*)&src[n];
    float4 a1 = *(const float4*)&src[n + 4];
    u16* dst = which == 0 ? &W12b[col*1024 + k]
             : which == 1 ? &W12b[col*1024 + 512 + k]
                          : &W3b[n];
    *(short8*)dst = cvt8(a0, a1);
}

// es[b][e] = sum of 16 partials; u[which][b][i] = sum_e W[e*512+i]*es; cd[b]
__global__ __launch_bounds__(256) void ucd_kernel(
    const float* __restrict__ W1, const float* __restrict__ W2,
    const float* __restrict__ b1, const float* __restrict__ b2,
    const double* __restrict__ part, double* __restrict__ u, double* __restrict__ cd)
{
    __shared__ double es[512];
    __shared__ double red[256];
    const int which = blockIdx.y;
    const int t = blockIdx.x * 256 + threadIdx.x;   // (b,i) flat
    const int b = t >> 9;
    const int i = t & 511;
    for (int e = threadIdx.x; e < 512; e += 256) {
        double a = 0.0;
        #pragma unroll
        for (int mt = 0; mt < 16; ++mt) a += part[mt*8192 + b*512 + e];
        es[e] = a;
    }
    __syncthreads();
    const float* W = which ? W2 : W1;
    double a = 0.0;
    for (int e = 0; e < 512; ++e) a += (double)W[e*512 + i] * es[e];
    u[which*8192 + t] = a;
    if (which == 0 && (blockIdx.x & 1) == 0) {
        double p = 0.0;
        for (int e = threadIdx.x; e < 512; e += 256) p += (double)(b1[e] + b2[e]) * es[e];
        red[threadIdx.x] = p;
        __syncthreads();
        for (int s = 128; s > 0; s >>= 1) {
            if (threadIdx.x < s) red[threadIdx.x] += red[threadIdx.x + s];
            __syncthreads();
        }
        if (threadIdx.x == 0) cd[b] = red[0];
    }
}

// Cast X|T -> XTb bf16 (row r: X[r,:] then T[r,:]) AND compute
// Sinv[r] = 1 / ( X[r,:]·u1[b] + T[r,:]·u2[b] + cd[b] ) in fp64. One wave/row.
__global__ __launch_bounds__(256) void castxt_kernel(
    const float* __restrict__ X, const float* __restrict__ T,
    const double* __restrict__ u, const double* __restrict__ cd,
    u16* __restrict__ XTb, float* __restrict__ Sinv)
{
    const int wave = threadIdx.x >> 6, lane = threadIdx.x & 63;
    const int r = blockIdx.x * 4 + wave;
    const int b = r & 15;
    const double* u1 = u + b*512;
    const double* u2 = u + 8192 + b*512;
    const int e = lane * 8;
    float4 x0 = *(const float4*)&X[r*512 + e];
    float4 x1 = *(const float4*)&X[r*512 + e + 4];
    float4 t0 = *(const float4*)&T[r*512 + e];
    float4 t1 = *(const float4*)&T[r*512 + e + 4];
    *(short8*)&XTb[r*1024 + e]       = cvt8(x0, x1);
    *(short8*)&XTb[r*1024 + 512 + e] = cvt8(t0, t1);
    double a = 0.0;
    a += (double)x0.x*u1[e+0] + (double)x0.y*u1[e+1] + (double)x0.z*u1[e+2] + (double)x0.w*u1[e+3];
    a += (double)x1.x*u1[e+4] + (double)x1.y*u1[e+5] + (double)x1.z*u1[e+6] + (double)x1.w*u1[e+7];
    a += (double)t0.x*u2[e+0] + (double)t0.y*u2[e+1] + (double)t0.z*u2[e+2] + (double)t0.w*u2[e+3];
    a += (double)t1.x*u2[e+4] + (double)t1.y*u2[e+5] + (double)t1.z*u2[e+6] + (double)t1.w*u2[e+7];
    #pragma unroll
    for (int off = 32; off > 0; off >>= 1) a += __shfl_down(a, off, 64);
    if (lane == 0) Sinv[r] = (float)(1.0 / (a + cd[b]));
}

extern "C" void kernel_launch(void* const* d_in, const int* in_sizes, int n_in,
                              void* d_out, int out_size, void* d_ws, size_t ws_size,
                              hipStream_t stream)
{
    const float* X   = (const float*)d_in[0];
    const float* Enc = (const float*)d_in[1];
    const float* T   = (const float*)d_in[2];
    const float* W1  = (const float*)d_in[3];
    const float* b1  = (const float*)d_in[4];
    const float* W2  = (const float*)d_in[5];
    const float* b2  = (const float*)d_in[6];
    const float* W3  = (const float*)d_in[7];
    const float* b3  = (const float*)d_in[8];
    float* out = (float*)d_out;

    char* w = (char*)d_ws;
    u16*    W12b  = (u16*)(w);                   //  1 MB
    u16*    W3b   = (u16*)(w + 1048576);         //  0.5 MB
    u16*    XTb   = (u16*)(w + 1572864);         // 32 MB (dead after gemm1)
    u16*    PT_bf = XTb;                          // 16 MB, aliases XTb
    u16*    HT_bf = (u16*)(w + 18350080);        //  8 MB, aliases XTb+16MB
    u16*    EncB  = (u16*)(w + 35127296);        // 16 MB
    u16*    EncT  = (u16*)(w + 51904512);        // 16 MB
    u16*    dvals = (u16*)(w + 68681728);        // 16 MB
    double* part  = (double*)(w + 85458944);     //  1 MB
    double* u     = (double*)(w + 86507520);     // 128 KB
    double* cd    = (double*)(w + 86638592);     // 128 B
    float*  Sinv  = (float*)(w + 86638720);      // 64 KB   (end ~82.7 MB)

    dim3 blk(256);
    castw_kernel <<<dim3(128, 3),    blk, 0, stream>>>(W1, W2, W3, W12b, W3b);
    enct_kernel  <<<dim3(8, 16, 16), blk, 0, stream>>>(Enc, EncT, EncB, part);
    ucd_kernel   <<<dim3(32, 2),     blk, 0, stream>>>(W1, W2, b1, b2, part, u, cd);
    castxt_kernel<<<dim3(4096),      blk, 0, stream>>>(X, T, u, cd, XTb, Sinv);

    gemm_mfma<1><<<dim3(4, 128, 1), blk, 0, stream>>>(XTb, W12b, b1, b2, b3, Sinv, dvals, out);
    gemm_mfma<2><<<dim3(8, 4, 16),  blk, 0, stream>>>(W3b, EncB, b1, b2, b3, Sinv, PT_bf, out);
    gemm_mfma<3><<<dim3(4, 4, 16),  blk, 0, stream>>>(PT_bf, EncT, b1, b2, b3, Sinv, HT_bf, out);
    gemm_mfma<4><<<dim3(4, 8, 16),  blk, 0, stream>>>(dvals, HT_bf, b1, b2, b3, Sinv, dvals, out);
}